// Round 1
// 117.750 us; speedup vs baseline: 1.0746x; 1.0746x over previous
//
#include <hip/hip_runtime.h>
#include <cstdint>

#define NB1 8192
#define NB2 8192
#define DDIM 128
#define KROW 256           // stored row: [hi(128) | lo(128)] f16
#define NSTEP 12           // virtual K = 384 (hi*hi + lo*hi + hi*lo), 32 f16/step

using half8   = __attribute__((ext_vector_type(8))) _Float16;
using half4   = __attribute__((ext_vector_type(4))) _Float16;
using float4v = __attribute__((ext_vector_type(4))) float;

typedef __attribute__((address_space(3))) void       lds_void;
typedef const __attribute__((address_space(1))) void glb_void;

__device__ inline unsigned long long packkey(float v, int j) {
  unsigned u = __float_as_uint(v);
  u = (u & 0x80000000u) ? ~u : (u | 0x80000000u);  // monotone float->uint
  return ((unsigned long long)u << 32) | (unsigned)j;
}

// virtual kt -> source 32-f16 chunk index within the [hi|lo] row
__device__ __forceinline__ int a_src(int kt) { return (kt < 8) ? kt : kt - 8; } // hi,lo,hi
__device__ __forceinline__ int b_src(int kt) { return (kt < 4) ? kt : kt - 4; } // hi,hi,lo

// ---------------------------------------------------------------------------
// Kernel 0: fp32 -> f16 hi/lo split (row = [hi|lo], 256 f16) + squared norms
// + init packed argmin keys. One wave per 2 rows; float4 loads, half4 stores.
// ---------------------------------------------------------------------------
__global__ __launch_bounds__(256) void convert_kernel(
    const float* __restrict__ d1, const float* __restrict__ d2,
    _Float16* __restrict__ A2, _Float16* __restrict__ B2,
    float* __restrict__ asq, float* __restrict__ bsq,
    unsigned long long* __restrict__ packed) {
  int gid  = blockIdx.x * 256 + threadIdx.x;
  int wv   = gid >> 6;
  int lane = gid & 63;
  int rowc = 2 * wv + (lane >> 5);
  bool isA = rowc < NB1;
  const float* src = isA ? d1 : d2;
  int row = isA ? rowc : rowc - NB1;
  int k4  = (lane & 31) * 4;

  float4 v = *(const float4*)&src[row * DDIM + k4];
  _Float16 h0 = (_Float16)v.x, h1 = (_Float16)v.y;
  _Float16 h2 = (_Float16)v.z, h3 = (_Float16)v.w;
  half4 hh = {h0, h1, h2, h3};
  half4 ll = {(_Float16)(v.x - (float)h0), (_Float16)(v.y - (float)h1),
              (_Float16)(v.z - (float)h2), (_Float16)(v.w - (float)h3)};

  _Float16* dst = (isA ? A2 : B2) + (size_t)row * KROW;
  *(half4*)&dst[k4]       = hh;
  *(half4*)&dst[128 + k4] = ll;

  float s = v.x * v.x + v.y * v.y + v.z * v.z + v.w * v.w;
  #pragma unroll
  for (int off = 16; off > 0; off >>= 1) s += __shfl_xor(s, off, 64);
  if ((lane & 31) == 0) (isA ? asq : bsq)[row] = s;

  if (gid < NB1) packed[gid] = 0xFFFFFFFFFFFFFFFFull;  // +inf key
}

// ---------------------------------------------------------------------------
// Kernel 1: MFMA GEMM (virtual K=384 f16, fp32 acc) + fused row argmin.
// 256x256 tile, 8 waves (4x2), each wave 4x8 mfma_f32_16x16x32_f16.
// Deep counted-vmcnt pipeline (T3+T4): 4-buffer LDS ring (128 KiB), depth-3
// prefetch, s_waitcnt vmcnt(8) + raw s_barrier per step — never drains to 0
// in the main loop. T5 setprio around the MFMA cluster. T2: bank-swizzled
// LDS cells (cell slot = (chunk + (row>>1)) & 3), staging fetches the
// inverse-permuted global chunk so global_load_lds stays linear-dest.
// Ledger: at top of step k the 8 newest in-flight loads are stages k+1,k+2,
// so vmcnt(8) guarantees stage(k) landed; barrier makes it block-wide.
// stage(k+3) targets the buffer read in step k-1 (retired at this barrier).
// ---------------------------------------------------------------------------
__global__ __launch_bounds__(512, 2) void mfma_match_kernel(
    const _Float16* __restrict__ A2, const _Float16* __restrict__ B2,
    const float* __restrict__ bsq, unsigned long long* __restrict__ packed) {
  __shared__ unsigned long long smem[16384];  // 128 KiB: 4 x (A 16KB | B 16KB)
  _Float16* S = (_Float16*)smem;

  const int t    = threadIdx.x;
  const int lane = t & 63;
  const int wid  = t >> 6;           // 0..7
  const int wm   = wid >> 1;         // 0..3 : 64-row band of A
  const int wn   = wid & 1;          // 0..1 : 128-col band of B
  const int lx   = lane & 15, q = lane >> 4;

  // XCD swizzle: 1024 blocks over 8 XCDs; per-XCD 16(bx) x 8(by) rectangle
  // -> resident set 16 A-panels (2 MB) + 8 B-panels (1 MB) < 4 MB L2.
  const int id  = blockIdx.x;
  const int xcd = id & 7, kk = id >> 3;          // kk 0..127
  const int bx = (xcd & 1) * 16 + (kk & 15);
  const int by = (xcd >> 1) * 8 + (kk >> 4);
  const int row0 = bx * 256, col0 = by * 256;

  // Staging lane geometry: call covers 128 rows; thread t -> row t>>2,
  // LDS slot t&3; global chunk = inverse bank-swizzle (slot - (row>>1)) & 3.
  const int rstg  = t >> 2;
  const int cslot = t & 3;

  float4v acc[4][8];
  #pragma unroll
  for (int m = 0; m < 4; ++m)
    #pragma unroll
    for (int c = 0; c < 8; ++c) acc[m][c] = (float4v){0.f, 0.f, 0.f, 0.f};

  // Prefetch bsq for the epilogue (drains early; vmcnt ledger unaffected —
  // the 8 newest in-flight at any step-top are always the 2 newest stages).
  const int jc0 = col0 + wn * 128 + lx;
  float bq[8];
  #pragma unroll
  for (int c = 0; c < 8; ++c) bq[c] = bsq[jc0 + 16 * c];

  auto stage = [&](int kt, int buf) {
    const int koA = a_src(kt) * 32, koB = b_src(kt) * 32;
    #pragma unroll
    for (int call = 0; call < 2; ++call) {
      const int R  = call * 128 + rstg;
      const int cc = (cslot - (R >> 1)) & 3;
      const _Float16* ga = A2 + (size_t)(row0 + R) * KROW + koA + cc * 8;
      __builtin_amdgcn_global_load_lds((glb_void*)ga,
          (lds_void*)(S + buf * 16384 + call * 4096 + wid * 512), 16, 0, 0);
      const _Float16* gb = B2 + (size_t)(col0 + R) * KROW + koB + cc * 8;
      __builtin_amdgcn_global_load_lds((glb_void*)gb,
          (lds_void*)(S + buf * 16384 + 8192 + call * 4096 + wid * 512), 16, 0, 0);
    }
  };

  const int sw = ((q + (lx >> 1)) & 3) * 8;   // bank-swizzled chunk offset

  auto compute = [&](int buf) {
    const _Float16* Ab = S + buf * 16384;
    const _Float16* Bb = Ab + 8192;
    half8 af[4], bf[8];
    #pragma unroll
    for (int m = 0; m < 4; ++m)
      af[m] = *(const half8*)&Ab[(wm * 64 + 16 * m + lx) * 32 + sw];
    #pragma unroll
    for (int c = 0; c < 8; ++c)
      bf[c] = *(const half8*)&Bb[(wn * 128 + 16 * c + lx) * 32 + sw];
    __builtin_amdgcn_s_setprio(1);
    #pragma unroll
    for (int m = 0; m < 4; ++m)
      #pragma unroll
      for (int c = 0; c < 8; ++c)
        acc[m][c] = __builtin_amdgcn_mfma_f32_16x16x32_f16(
            af[m], bf[c], acc[m][c], 0, 0, 0);
    __builtin_amdgcn_s_setprio(0);
  };

  // Prologue: depth-3 prefetch (12 loads/thread in flight).
  stage(0, 0); stage(1, 1); stage(2, 2);

#define STEP(K, N)                                                    \
  do {                                                                \
    asm volatile("s_waitcnt vmcnt(" #N ")" ::: "memory");             \
    __builtin_amdgcn_s_barrier();                                     \
    asm volatile("" ::: "memory");                                    \
    if constexpr ((K) + 3 < NSTEP) stage((K) + 3, ((K) + 3) & 3);     \
    compute((K) & 3);                                                 \
  } while (0)

  STEP(0, 8);  STEP(1, 8);  STEP(2, 8);  STEP(3, 8);
  STEP(4, 8);  STEP(5, 8);  STEP(6, 8);  STEP(7, 8);
  STEP(8, 8);  STEP(9, 8);  STEP(10, 4); STEP(11, 0);
#undef STEP

  // ---- Epilogue. C/D layout: col = lane&15, row = q*4 + reg. ----
  __syncthreads();  // vmcnt fully drained (STEP 11 waited 0); frag reads done
  #pragma unroll
  for (int m = 0; m < 4; ++m) {
    #pragma unroll
    for (int reg = 0; reg < 4; ++reg) {
      float bv = 1e30f; int bj = 0;
      #pragma unroll
      for (int c = 0; c < 8; ++c) {  // j ascending -> strict < keeps min j
        float val = fmaf(-2.f, acc[m][c][reg], bq[c]);
        if (val < bv) { bv = val; bj = jc0 + 16 * c; }
      }
      const int mrow = wm * 64 + 16 * m + 4 * q + reg;
      smem[mrow * 33 + wn * 16 + lx] = packkey(bv, bj);  // pad-33: no 16-way
    }
  }
  __syncthreads();
  if (t < 256) {
    unsigned long long best = ~0ull;
    #pragma unroll
    for (int c = 0; c < 32; ++c) {   // rotated read: spread banks across rows
      unsigned long long kx = smem[t * 33 + ((2 * t + c) & 31)];
      if (kx < best) best = kx;
    }
    atomicMin(&packed[row0 + t], best);  // device-scope; lex (val, idx) min
  }
}

// ---------------------------------------------------------------------------
// Kernel 2: decode packed keys, write outputs.
// ---------------------------------------------------------------------------
__global__ __launch_bounds__(256) void out_kernel(
    const unsigned long long* __restrict__ packed,
    const float* __restrict__ asq, float* __restrict__ out) {
  int r = blockIdx.x * 256 + threadIdx.x;
  unsigned long long best = packed[r];
  unsigned u = (unsigned)(best >> 32);
  u = (u & 0x80000000u) ? (u & 0x7fffffffu) : ~u;   // invert monotone map
  float val  = __uint_as_float(u);
  float dist = sqrtf(fmaxf(asq[r] + val, 0.f));
  int j = (int)(unsigned)(best & 0xffffffffu);
  out[r]               = dist;
  out[NB1 + 2 * r]     = (float)r;
  out[NB1 + 2 * r + 1] = (float)j;
}

extern "C" void kernel_launch(void* const* d_in, const int* in_sizes, int n_in,
                              void* d_out, int out_size, void* d_ws, size_t ws_size,
                              hipStream_t stream) {
  const float* d1 = (const float*)d_in[0];
  const float* d2 = (const float*)d_in[1];
  float* out = (float*)d_out;

  char* w = (char*)d_ws;
  float* asq = (float*)w;                                   // 32 KB
  float* bsq = (float*)(w + 32768);                         // 32 KB
  _Float16* A2 = (_Float16*)(w + 65536);                    // 4 MB
  _Float16* B2 = (_Float16*)(w + 65536 + 4194304);          // 4 MB
  unsigned long long* packed =
      (unsigned long long*)(w + 65536 + 2 * 4194304);       // 64 KB

  convert_kernel<<<(NB1 + NB2) / 8, 256, 0, stream>>>(
      d1, d2, A2, B2, asq, bsq, packed);

  mfma_match_kernel<<<(NB1 / 256) * (NB2 / 256), 512, 0, stream>>>(
      A2, B2, bsq, packed);

  out_kernel<<<NB1 / 256, 256, 0, stream>>>(packed, asq, out);
}